// Round 2
// baseline (292.344 us; speedup 1.0000x reference)
//
#include <hip/hip_runtime.h>
#include <hip/hip_bf16.h>
#include <cfloat>

// VQ-VAE vector quantizer.  N=262144 rows x D=100, K=512 codes.
// out[0..N*D-1] = quantized (fp32-exact gather); out[N*D]=mse; out[N*D+1]=0.25*mse.
//
// R7: occupancy-first restructure.
//  Post-mortem R6: deleting barriers regressed (104->114us) -- barriers were not
//  the cost; per-iter L2 B-loads were.  Both R5/R6 sit at ~20% HBM / ~13% MFMA /
//  ~22% VALU with ~8 waves/CU resident => stall-bound on unhidden latency, and
//  the 1024-block grid only offers 4 blocks/CU with ~2 actually resident.
//  R7: 512-thread blocks (8 waves, 512 rows), grid=512 => 2 blocks/CU, and the
//  FULL codebook staged through a single 64 KB LDS buffer in two halves:
//   - LDS/block ~69.7 KB  => 2 blocks/CU co-resident = 16 waves/CU (2x R5)
//   - barriers: 4/block (vs R5's 16) -- 16 barrier-free inner iterations
//     between any two barriers
//   - B fragments via the R5-proven conflict-free lane-linear ds_read_b128
//   - half 1 register-prefetched during half-0 compute (one-time, 32 VGPRs;
//     compiler may sink under pressure -- acceptable either way)
//  A prologue (28-deep ILP batch) and coalesced g/25 epilogue kept.
//
// ws: ws_f[0] = loss accum; ws_f[16..528) = e2[k] (fp32);
//     bytes [4096..4096+131072): bf16 cb; chunk c granule layout (16B granules):
//     granule g = (s*2+tt)*64 + quad*16 + lr  holds code (c*32+tt*16+lr),
//     k = s*32+quad*8+{0..7}  (zero-padded for k>=100).

#define N_ROWS (64 * 64 * 64)
#define D 100
#define KCODES 512
#define CB_OFF 4096
#define E2_OFF 16

typedef __attribute__((ext_vector_type(8))) short short8;
typedef __attribute__((ext_vector_type(4))) float f32x4;

__device__ __forceinline__ unsigned short f2bf(float f) {
    union { float f; unsigned u; } v; v.f = f;
    unsigned r = v.u + 0x7FFF + ((v.u >> 16) & 1);   // RNE
    return (unsigned short)(r >> 16);
}
__device__ __forceinline__ unsigned pk2(float a, float b) {   // packed bf16 cvt (RNE)
    union { __hip_bfloat162 h; unsigned u; } c;
    c.h = __float22bfloat162_rn(make_float2(a, b));
    return c.u;
}
__device__ __forceinline__ short8 pack8(const float4& a, const float4& b) {
    union { unsigned u[4]; short8 v; } r;
    r.u[0] = pk2(a.x, a.y); r.u[1] = pk2(a.z, a.w);
    r.u[2] = pk2(b.x, b.y); r.u[3] = pk2(b.z, b.w);
    return r.v;
}

// ---- init: one wave per code ----
__global__ __launch_bounds__(64) void vq_init(const float* __restrict__ emb,
                                              float* __restrict__ ws) {
    const int code = blockIdx.x, l = threadIdx.x;
    const float* e = emb + code * D;
    if (code == 0 && l == 0) ws[0] = 0.0f;
    float a = e[l];
    float b = (l < D - 64) ? e[64 + l] : 0.0f;
    float p = fmaf(a, a, b * b);
#pragma unroll
    for (int off = 32; off; off >>= 1) p += __shfl_xor(p, off);
    if (l == 0) ws[E2_OFF + code] = p;

    // cb granules: 16 per code, written by lanes 0..15 (8 shorts each)
    if (l < 16) {
        const int s = l >> 2, q = l & 3;
        short8 v;
#pragma unroll
        for (int j = 0; j < 8; ++j) {
            int k = s * 32 + q * 8 + j;
            v[j] = (k < D) ? (short)f2bf(e[k]) : (short)0;
        }
        const int chunk = code >> 5, ci = code & 31;
        const int tt = ci >> 4, lr = ci & 15;
        unsigned short* cb = (unsigned short*)((char*)ws + CB_OFF);
        // short offset = chunk*4096 + granule*8, granule = (s*2+tt)*64 + q*16 + lr
        *(short8*)(cb + chunk * 4096 + ((s * 2 + tt) * 64 + q * 16 + lr) * 8) = v;
    }
}

// ---- main: 8 waves/block, 64 rows/wave (M=4), codebook via 64KB LDS halves ----
__global__ __launch_bounds__(512, 4) void vq_main(const float* __restrict__ x,
                                                  const float* __restrict__ emb,
                                                  float* __restrict__ ws,
                                                  float* __restrict__ out) {
    __shared__ uint4  sbuf[4096];     // 64 KB: half the codebook (8 chunks)
    __shared__ float  e2s[KCODES];    // 2 KB
    __shared__ int    widx[512];      // 2 KB
    __shared__ float  wsum[8];

    const int tid = threadIdx.x, wave = tid >> 6, lane = tid & 63;
    const int quad = lane >> 4, lr = lane & 15;
    const long brow = (long)blockIdx.x * 512;
    const long wrow = brow + wave * 64;

    // ---- A: 28 independent scattered loads (batched), then convert ----
    float4 av[4][7];
#pragma unroll
    for (int m = 0; m < 4; ++m) {
        const float* xr = x + (wrow + m * 16 + lr) * D + quad * 8;
        av[m][0] = *(const float4*)(xr);
        av[m][1] = *(const float4*)(xr + 4);
        av[m][2] = *(const float4*)(xr + 32);
        av[m][3] = *(const float4*)(xr + 36);
        av[m][4] = *(const float4*)(xr + 64);
        av[m][5] = *(const float4*)(xr + 68);
        av[m][6] = *(const float4*)(x + (wrow + m * 16 + lr) * D + 96);  // same addr all quads
    }

    // ---- stage half 0 of the codebook + e2 (issued while A loads in flight) ----
    const uint4* __restrict__ cbg = (const uint4*)((const char*)ws + CB_OFF);
    const float* __restrict__ e2g = ws + E2_OFF;
    uint4 h0[8];
#pragma unroll
    for (int k = 0; k < 8; ++k) h0[k] = cbg[tid + k * 512];
    e2s[tid] = e2g[tid];

    // ---- convert A -> fragments + fp32 norms ----
    short8 A[4][4];
    float  xnorm[4];
#pragma unroll
    for (int m = 0; m < 4; ++m) {
        float4 z = av[m][6];
        if (quad != 0) z = make_float4(0.f, 0.f, 0.f, 0.f);   // tail only in quad 0
        float nrm = 0.f;
#pragma unroll
        for (int i = 0; i < 6; ++i) {
            float4 f = av[m][i];
            nrm = fmaf(f.x, f.x, nrm); nrm = fmaf(f.y, f.y, nrm);
            nrm = fmaf(f.z, f.z, nrm); nrm = fmaf(f.w, f.w, nrm);
        }
        nrm = fmaf(z.x, z.x, nrm); nrm = fmaf(z.y, z.y, nrm);
        nrm = fmaf(z.z, z.z, nrm); nrm = fmaf(z.w, z.w, nrm);
        A[m][0] = pack8(av[m][0], av[m][1]);
        A[m][1] = pack8(av[m][2], av[m][3]);
        A[m][2] = pack8(av[m][4], av[m][5]);
        A[m][3] = pack8(z, make_float4(0.f, 0.f, 0.f, 0.f));
        nrm += __shfl_xor(nrm, 16);
        nrm += __shfl_xor(nrm, 32);
        xnorm[m] = nrm;
    }

#pragma unroll
    for (int k = 0; k < 8; ++k) sbuf[tid + k * 512] = h0[k];

    // prefetch half 1 into regs (in flight across half-0 compute; compiler may sink)
    uint4 h1[8];
#pragma unroll
    for (int k = 0; k < 8; ++k) h1[k] = cbg[4096 + tid + k * 512];

    __syncthreads();                                   // half 0 + e2 visible

    float    runmin[4][4];
    unsigned runidx[4][4];
#pragma unroll
    for (int m = 0; m < 4; ++m)
#pragma unroll
        for (int r = 0; r < 4; ++r) { runmin[m][r] = FLT_MAX; runidx[m][r] = 0; }

    const short8* __restrict__ sbl = (const short8*)sbuf;

#pragma unroll 1
    for (int h = 0; h < 2; ++h) {
        if (h == 1) {
            __syncthreads();                           // all waves done reading half 0
#pragma unroll
            for (int k = 0; k < 8; ++k) sbuf[tid + k * 512] = h1[k];
            __syncthreads();                           // half 1 visible
        }
#pragma unroll 1
        for (int c8 = 0; c8 < 8; ++c8) {
            const int c = h * 8 + c8;
#pragma unroll
            for (int tt = 0; tt < 2; ++tt) {
                // B fragments: lane-linear ds_read_b128, conflict-free (R5-proven)
                short8 B[4];
#pragma unroll
                for (int s = 0; s < 4; ++s) B[s] = sbl[c8 * 512 + (s * 2 + tt) * 64 + lane];
                float e2v = e2s[c * 32 + tt * 16 + lr];

                f32x4 acc[4];
#pragma unroll
                for (int m = 0; m < 4; ++m) acc[m] = (f32x4){0.f, 0.f, 0.f, 0.f};
#pragma unroll
                for (int s = 0; s < 4; ++s)
#pragma unroll
                    for (int m = 0; m < 4; ++m)
                        acc[m] = __builtin_amdgcn_mfma_f32_16x16x32_bf16(A[m][s], B[s], acc[m], 0, 0, 0);

                // fold: score = e2 - 2<x,e>; C layout row=quad*4+r, col=lr
                const unsigned code = c * 32 + tt * 16 + lr;
#pragma unroll
                for (int m = 0; m < 4; ++m)
#pragma unroll
                    for (int r = 0; r < 4; ++r) {
                        float sc = fmaf(-2.0f, acc[m][r], e2v);
                        if (sc < runmin[m][r]) { runmin[m][r] = sc; runidx[m][r] = code; }
                    }
            }
        }
    }

    // ---- per-row argmin across the 16 columns (xor 8,4,2,1 stays in quad) ----
    float lsum = 0.0f;
#pragma unroll
    for (int m = 0; m < 4; ++m)
#pragma unroll
        for (int r = 0; r < 4; ++r) {
            float    s = runmin[m][r];
            unsigned i = runidx[m][r];
#pragma unroll
            for (int off = 8; off >= 1; off >>= 1) {
                float    os = __shfl_xor(s, off);
                unsigned oi = (unsigned)__shfl_xor((int)i, off);
                if (os < s || (os == s && oi < i)) { s = os; i = oi; }
            }
            if (lr == quad * 4 + r) {                  // writer lane for this row
                lsum += xnorm[m] + s;                  // ||x||^2 + e2 - 2<x,e>
                widx[wave * 64 + m * 16 + quad * 4 + r] = (int)i;
            }
        }
#pragma unroll
    for (int off = 32; off >= 1; off >>= 1) lsum += __shfl_xor(lsum, off);
    if (lane == 0) wsum[wave] = lsum;
    __syncthreads();                                   // wsum + widx visible
    if (tid == 0) {
        float t = 0.f;
#pragma unroll
        for (int w = 0; w < 8; ++w) t += wsum[w];
        atomicAdd(ws, t);
    }

    // ---- coalesced epilogue: 12800 float4 = 512 rows x 25, batched 5-deep ----
    const float4* __restrict__ ef = (const float4*)emb;   // 25 float4 per row, exact
    float4* __restrict__ og = (float4*)(out + brow * D);
#pragma unroll
    for (int i = 0; i < 25; i += 5) {
        float4 q[5];
        int    gi[5];
#pragma unroll
        for (int u = 0; u < 5; ++u) {
            int g = (i + u) * 512 + tid;
            int row = g / 25;                 // const-divisor magic div
            int c4  = g - row * 25;
            gi[u] = g;
            q[u]  = ef[(long)widx[row] * 25 + c4];
        }
#pragma unroll
        for (int u = 0; u < 5; ++u) og[gi[u]] = q[u];
    }
}

// ---- finalize ----
__global__ void vq_final(const float* __restrict__ ws, float* __restrict__ out) {
    float mse = ws[0] / (float)((long)N_ROWS * D);
    out[(long)N_ROWS * D]     = mse;
    out[(long)N_ROWS * D + 1] = 0.25f * mse;
}

extern "C" void kernel_launch(void* const* d_in, const int* in_sizes, int n_in,
                              void* d_out, int out_size, void* d_ws, size_t ws_size,
                              hipStream_t stream) {
    const float* x   = (const float*)d_in[0];
    const float* emb = (const float*)d_in[1];
    float* out = (float*)d_out;
    float* ws  = (float*)d_ws;

    vq_init<<<KCODES, 64, 0, stream>>>(emb, ws);
    vq_main<<<N_ROWS / 512, 512, 0, stream>>>(x, emb, ws, out);
    vq_final<<<1, 1, 0, stream>>>(ws, out);
}

// Round 3
// 237.882 us; speedup vs baseline: 1.2289x; 1.2289x over previous
//
#include <hip/hip_runtime.h>
#include <hip/hip_bf16.h>
#include <cfloat>

// VQ-VAE vector quantizer.  N=262144 rows x D=100, K=512 codes.
// out[0..N*D-1] = quantized (fp32-exact gather); out[N*D]=mse; out[N*D+1]=0.25*mse.
//
// R8: R5 structure at 8 waves/block.
//  Post-mortem R7: launch_bounds(512,4) capped VGPR at 64 -> massive scratch
//  spill (FETCH +82MB, WRITE +116MB) = the whole regression.  But occupancy DID
//  rise 20->40% and HBM BW 1.55->2.25 TB/s: the 8-wave block worked, the reg cap
//  killed it.  Across R5/R6/R7 resident BLOCKS/CU is pinned at ~1.6-2 regardless
//  of block size, so waves/CU scales with block size.
//  R8 = R5's proven math (chunked 8KB double-buffered B in LDS, conflict-free
//  lane-linear granule reads, 28-deep A prologue, coalesced g/25 epilogue) with:
//   - 512-thread blocks (8 waves, 512 rows), grid = 512
//   - __launch_bounds__(512, 2): VGPR cap 256, compiler lands ~88 as in R5
//     => 2 blocks/CU co-resident by VGPR AND LDS => ~16 waves/CU
//   - staging: 1 granule/thread/chunk (was 2), e2 in one load
//  Tripwires: VGPR_Count must be ~88-110 (not 64); WRITE_SIZE must be 102432.
//
// ws: ws_f[0] = loss accum; ws_f[16..528) = e2[k] (fp32);
//     bytes [4096..4096+131072): bf16 cb; chunk c granule layout (16B granules):
//     granule g = (s*2+tt)*64 + quad*16 + lr  holds code (c*32+tt*16+lr),
//     k = s*32+quad*8+{0..7}  (zero-padded for k>=100).

#define N_ROWS (64 * 64 * 64)
#define D 100
#define KCODES 512
#define CB_OFF 4096
#define E2_OFF 16

typedef __attribute__((ext_vector_type(8))) short short8;
typedef __attribute__((ext_vector_type(4))) float f32x4;

__device__ __forceinline__ unsigned short f2bf(float f) {
    union { float f; unsigned u; } v; v.f = f;
    unsigned r = v.u + 0x7FFF + ((v.u >> 16) & 1);   // RNE
    return (unsigned short)(r >> 16);
}
__device__ __forceinline__ unsigned pk2(float a, float b) {   // packed bf16 cvt (RNE)
    union { __hip_bfloat162 h; unsigned u; } c;
    c.h = __float22bfloat162_rn(make_float2(a, b));
    return c.u;
}
__device__ __forceinline__ short8 pack8(const float4& a, const float4& b) {
    union { unsigned u[4]; short8 v; } r;
    r.u[0] = pk2(a.x, a.y); r.u[1] = pk2(a.z, a.w);
    r.u[2] = pk2(b.x, b.y); r.u[3] = pk2(b.z, b.w);
    return r.v;
}

// ---- init: one wave per code ----
__global__ __launch_bounds__(64) void vq_init(const float* __restrict__ emb,
                                              float* __restrict__ ws) {
    const int code = blockIdx.x, l = threadIdx.x;
    const float* e = emb + code * D;
    if (code == 0 && l == 0) ws[0] = 0.0f;
    float a = e[l];
    float b = (l < D - 64) ? e[64 + l] : 0.0f;
    float p = fmaf(a, a, b * b);
#pragma unroll
    for (int off = 32; off; off >>= 1) p += __shfl_xor(p, off);
    if (l == 0) ws[E2_OFF + code] = p;

    // cb granules: 16 per code, written by lanes 0..15 (8 shorts each)
    if (l < 16) {
        const int s = l >> 2, q = l & 3;
        short8 v;
#pragma unroll
        for (int j = 0; j < 8; ++j) {
            int k = s * 32 + q * 8 + j;
            v[j] = (k < D) ? (short)f2bf(e[k]) : (short)0;
        }
        const int chunk = code >> 5, ci = code & 31;
        const int tt = ci >> 4, lr = ci & 15;
        unsigned short* cb = (unsigned short*)((char*)ws + CB_OFF);
        // short offset = chunk*4096 + granule*8, granule = (s*2+tt)*64 + q*16 + lr
        *(short8*)(cb + chunk * 4096 + ((s * 2 + tt) * 64 + q * 16 + lr) * 8) = v;
    }
}

// ---- main: 8 waves/block, 64 rows/wave (M=4), B via double-buffered LDS ----
__global__ __launch_bounds__(512, 2) void vq_main(const float* __restrict__ x,
                                                  const float* __restrict__ emb,
                                                  float* __restrict__ ws,
                                                  float* __restrict__ out) {
    __shared__ uint4  bbuf[2][512];   // 2 x 8 KB B chunk buffers
    __shared__ float  e2s[KCODES];    // 2 KB
    __shared__ int    widx[512];      // 2 KB
    __shared__ float  wsum[8];

    const int tid = threadIdx.x, wave = tid >> 6, lane = tid & 63;
    const int quad = lane >> 4, lr = lane & 15;
    const long brow = (long)blockIdx.x * 512;
    const long wrow = brow + wave * 64;

    // ---- A: 28 independent scattered loads (batched), then convert ----
    float4 av[4][7];
#pragma unroll
    for (int m = 0; m < 4; ++m) {
        const float* xr = x + (wrow + m * 16 + lr) * D + quad * 8;
        av[m][0] = *(const float4*)(xr);
        av[m][1] = *(const float4*)(xr + 4);
        av[m][2] = *(const float4*)(xr + 32);
        av[m][3] = *(const float4*)(xr + 36);
        av[m][4] = *(const float4*)(xr + 64);
        av[m][5] = *(const float4*)(xr + 68);
        av[m][6] = *(const float4*)(x + (wrow + m * 16 + lr) * D + 96);  // same addr all quads
    }

    // ---- B chunk 0 + e2 staging (issued while A loads are in flight) ----
    const uint4* __restrict__ cbg = (const uint4*)((const char*)ws + CB_OFF);
    uint4 st0 = cbg[tid];                 // one granule per thread (8 KB / 512)
    const float* __restrict__ e2g = ws + E2_OFF;
    e2s[tid] = e2g[tid];

    // ---- convert A -> fragments + fp32 norms ----
    short8 A[4][4];
    float  xnorm[4];
#pragma unroll
    for (int m = 0; m < 4; ++m) {
        float4 z = av[m][6];
        if (quad != 0) z = make_float4(0.f, 0.f, 0.f, 0.f);   // tail only in quad 0
        float nrm = 0.f;
#pragma unroll
        for (int i = 0; i < 6; ++i) {
            float4 f = av[m][i];
            nrm = fmaf(f.x, f.x, nrm); nrm = fmaf(f.y, f.y, nrm);
            nrm = fmaf(f.z, f.z, nrm); nrm = fmaf(f.w, f.w, nrm);
        }
        nrm = fmaf(z.x, z.x, nrm); nrm = fmaf(z.y, z.y, nrm);
        nrm = fmaf(z.z, z.z, nrm); nrm = fmaf(z.w, z.w, nrm);
        A[m][0] = pack8(av[m][0], av[m][1]);
        A[m][1] = pack8(av[m][2], av[m][3]);
        A[m][2] = pack8(av[m][4], av[m][5]);
        A[m][3] = pack8(z, make_float4(0.f, 0.f, 0.f, 0.f));
        nrm += __shfl_xor(nrm, 16);
        nrm += __shfl_xor(nrm, 32);
        xnorm[m] = nrm;
    }

    bbuf[0][tid] = st0;
    __syncthreads();

    float    runmin[4][4];
    unsigned runidx[4][4];
#pragma unroll
    for (int m = 0; m < 4; ++m)
#pragma unroll
        for (int r = 0; r < 4; ++r) { runmin[m][r] = FLT_MAX; runidx[m][r] = 0; }

    for (int c = 0; c < 16; ++c) {
        const int p = c & 1;
        uint4 n0;
        if (c < 15) n0 = cbg[(c + 1) * 512 + tid];   // prefetch next chunk into regs

        // B fragments: lane-linear ds_read_b128, conflict-free
        const short8* __restrict__ bl = (const short8*)&bbuf[p][0];
        short8 B[2][4];
#pragma unroll
        for (int s = 0; s < 4; ++s) {
            B[0][s] = bl[(s * 2 + 0) * 64 + lane];
            B[1][s] = bl[(s * 2 + 1) * 64 + lane];
        }
        float e2v0 = e2s[c * 32 + lr];
        float e2v1 = e2s[c * 32 + 16 + lr];

        f32x4 acc[4][2];
#pragma unroll
        for (int m = 0; m < 4; ++m) {
            acc[m][0] = (f32x4){0.f, 0.f, 0.f, 0.f};
            acc[m][1] = (f32x4){0.f, 0.f, 0.f, 0.f};
        }
#pragma unroll
        for (int s = 0; s < 4; ++s)
#pragma unroll
            for (int m = 0; m < 4; ++m) {
                acc[m][0] = __builtin_amdgcn_mfma_f32_16x16x32_bf16(A[m][s], B[0][s], acc[m][0], 0, 0, 0);
                acc[m][1] = __builtin_amdgcn_mfma_f32_16x16x32_bf16(A[m][s], B[1][s], acc[m][1], 0, 0, 0);
            }

        // fold: score = e2 - 2<x,e>; C layout row=quad*4+r, col=lr
#pragma unroll
        for (int m = 0; m < 4; ++m)
#pragma unroll
            for (int tt = 0; tt < 2; ++tt) {
                float e2v = tt ? e2v1 : e2v0;
                unsigned code = c * 32 + tt * 16 + lr;
#pragma unroll
                for (int r = 0; r < 4; ++r) {
                    float sc = fmaf(-2.0f, acc[m][tt][r], e2v);
                    if (sc < runmin[m][r]) { runmin[m][r] = sc; runidx[m][r] = code; }
                }
            }

        if (c < 15) bbuf[p ^ 1][tid] = n0;
        __syncthreads();
    }

    // ---- per-row argmin across the 16 columns (xor 8,4,2,1 stays in quad) ----
    float lsum = 0.0f;
#pragma unroll
    for (int m = 0; m < 4; ++m)
#pragma unroll
        for (int r = 0; r < 4; ++r) {
            float    s = runmin[m][r];
            unsigned i = runidx[m][r];
#pragma unroll
            for (int off = 8; off >= 1; off >>= 1) {
                float    os = __shfl_xor(s, off);
                unsigned oi = (unsigned)__shfl_xor((int)i, off);
                if (os < s || (os == s && oi < i)) { s = os; i = oi; }
            }
            if (lr == quad * 4 + r) {                  // writer lane for this row
                lsum += xnorm[m] + s;                  // ||x||^2 + e2 - 2<x,e>
                widx[wave * 64 + m * 16 + quad * 4 + r] = (int)i;
            }
        }
#pragma unroll
    for (int off = 32; off >= 1; off >>= 1) lsum += __shfl_xor(lsum, off);
    if (lane == 0) wsum[wave] = lsum;
    __syncthreads();                                   // wsum + widx visible
    if (tid == 0) {
        float t = 0.f;
#pragma unroll
        for (int w = 0; w < 8; ++w) t += wsum[w];
        atomicAdd(ws, t);
    }

    // ---- coalesced epilogue: 12800 float4 = 512 rows x 25, batched 5-deep ----
    const float4* __restrict__ ef = (const float4*)emb;   // 25 float4 per row, exact
    float4* __restrict__ og = (float4*)(out + brow * D);
#pragma unroll
    for (int i = 0; i < 25; i += 5) {
        float4 q[5];
        int    gi[5];
#pragma unroll
        for (int u = 0; u < 5; ++u) {
            int g = (i + u) * 512 + tid;
            int row = g / 25;                 // const-divisor magic div
            int c4  = g - row * 25;
            gi[u] = g;
            q[u]  = ef[(long)widx[row] * 25 + c4];
        }
#pragma unroll
        for (int u = 0; u < 5; ++u) og[gi[u]] = q[u];
    }
}

// ---- finalize ----
__global__ void vq_final(const float* __restrict__ ws, float* __restrict__ out) {
    float mse = ws[0] / (float)((long)N_ROWS * D);
    out[(long)N_ROWS * D]     = mse;
    out[(long)N_ROWS * D + 1] = 0.25f * mse;
}

extern "C" void kernel_launch(void* const* d_in, const int* in_sizes, int n_in,
                              void* d_out, int out_size, void* d_ws, size_t ws_size,
                              hipStream_t stream) {
    const float* x   = (const float*)d_in[0];
    const float* emb = (const float*)d_in[1];
    float* out = (float*)d_out;
    float* ws  = (float*)d_ws;

    vq_init<<<KCODES, 64, 0, stream>>>(emb, ws);
    vq_main<<<N_ROWS / 512, 512, 0, stream>>>(x, emb, ws, out);
    vq_final<<<1, 1, 0, stream>>>(ws, out);
}